// Round 8
// baseline (4589.212 us; speedup 1.0000x reference)
//
#include <hip/hip_runtime.h>
#include <hip/hip_bf16.h>
#include <math.h>

#define SEQ 1024
#define HID 512
#define FOURH 2048
#define IND 400
#define NT 13

#define TAG_INVALID 0xFFFFFFFFu

__device__ __forceinline__ float bf2f(unsigned short u) {
    union { unsigned u32; float f; } v;
    v.u32 = ((unsigned)u) << 16;
    return v.f;
}

__device__ __forceinline__ unsigned short f2bf(float f) {
    union { float f; unsigned u; } v;
    v.f = f;
    unsigned u = v.u;
    unsigned rounding = 0x7FFFu + ((u >> 16) & 1u);
    u += rounding;
    return (unsigned short)(u >> 16);
}

// dtype-agnostic float load: isf32 selects f32 vs bf16 interpretation
__device__ __forceinline__ float ldf(const void* p, size_t i, int isf32) {
    return isf32 ? ((const float*)p)[i] : bf2f(((const unsigned short*)p)[i]);
}

// fast transcendentals: v_exp_f32 / v_rcp_f32 based; abs err ~1e-7
__device__ __forceinline__ float fsigm(float x) {
    return __builtin_amdgcn_rcpf(1.f + __builtin_amdgcn_exp2f(-1.44269504f * x));
}
__device__ __forceinline__ float ftanhf(float x) {
    return 1.f - 2.f * __builtin_amdgcn_rcpf(__builtin_amdgcn_exp2f(2.88539008f * x) + 1.f);
}
// saturating clamp (also squashes NaN from any garbage input)
__device__ __forceinline__ float satz(float z) { return fminf(fmaxf(z, -60.f), 60.f); }

// ---------------------------------------------------------------- input dtype detection + counter zero
__global__ __launch_bounds__(64) void detect_kernel(const unsigned short* __restrict__ w,
                                                    int* __restrict__ flag,
                                                    unsigned* __restrict__ vcnt) {
    int lane = threadIdx.x;
    int cnt = 0;
    for (int i = 0; i < 4; ++i) {
        unsigned short u = w[2 * (lane * 4 + i)];   // low half if buffer is f32
        int e = (u >> 7) & 0xFF;
        if (e >= 90 && e < 127) cnt++;
    }
#pragma unroll
    for (int off = 32; off >= 1; off >>= 1) cnt += __shfl_xor(cnt, off, 64);
    if (lane == 0) *flag = (cnt < 128) ? 1 : 0;    // 1 => inputs are float32
    if (lane == 1) *vcnt = 0;                      // outproj->viterbi completion counter
}

// ---------------------------------------------------------------- pre = feat @ Wx + b (embed fused, both dirs), bf16 out
__global__ __launch_bounds__(256) void pre_gemm_kernel(
        const int* __restrict__ x, const int* __restrict__ cas, const int* __restrict__ pos,
        const void* __restrict__ W_emb, const void* __restrict__ W_cas, const void* __restrict__ W_pos,
        const void* __restrict__ Wx_f, const void* __restrict__ b_f,
        const void* __restrict__ Wx_b, const void* __restrict__ b_b,
        unsigned short* __restrict__ pre, const int* __restrict__ dflag) {
    __shared__ float ftile[32 * IND];    // 51.2 KB
    __shared__ int idxs[96];
    const int isf32 = *dflag;
    int dir = blockIdx.z;
    const void* Wx = dir ? Wx_b : Wx_f;
    const void* bb = dir ? b_b : b_f;
    unsigned short* pre_d = pre + (size_t)dir * SEQ * FOURH;
    int r0 = blockIdx.y * 32;
    int col = blockIdx.x * 256 + threadIdx.x;
    int tid = threadIdx.x;

    if (tid < 32)       idxs[tid] = x[r0 + tid];
    else if (tid < 64)  idxs[tid] = cas[r0 + tid - 32];
    else if (tid < 96)  idxs[tid] = pos[r0 + tid - 64];
    __syncthreads();

    for (int idx = tid; idx < 32 * IND; idx += 256) {
        int r = idx / IND;
        int e = idx - r * IND;
        float v;
        if (e < 300)      v = ldf(W_emb, (size_t)idxs[r] * 300 + e, isf32);
        else if (e < 350) v = ldf(W_cas, (size_t)idxs[32 + r] * 50 + (e - 300), isf32);
        else              v = ldf(W_pos, (size_t)idxs[64 + r] * 50 + (e - 350), isf32);
        ftile[idx] = v;
    }
    __syncthreads();

    float acc[32];
    float bias = ldf(bb, col, isf32);
#pragma unroll
    for (int r = 0; r < 32; ++r) acc[r] = bias;

    if (isf32) {
        const float* W = (const float*)Wx;
        for (int kk = 0; kk < 100; ++kk) {
            int k = kk * 4;
            float w0 = W[(size_t)(k + 0) * FOURH + col];
            float w1 = W[(size_t)(k + 1) * FOURH + col];
            float w2 = W[(size_t)(k + 2) * FOURH + col];
            float w3 = W[(size_t)(k + 3) * FOURH + col];
#pragma unroll
            for (int r = 0; r < 32; ++r) {
                float4 f = *(const float4*)&ftile[r * IND + k];
                acc[r] += f.x * w0 + f.y * w1 + f.z * w2 + f.w * w3;
            }
        }
    } else {
        const unsigned short* W = (const unsigned short*)Wx;
        for (int kk = 0; kk < 100; ++kk) {
            int k = kk * 4;
            float w0 = bf2f(W[(size_t)(k + 0) * FOURH + col]);
            float w1 = bf2f(W[(size_t)(k + 1) * FOURH + col]);
            float w2 = bf2f(W[(size_t)(k + 2) * FOURH + col]);
            float w3 = bf2f(W[(size_t)(k + 3) * FOURH + col]);
#pragma unroll
            for (int r = 0; r < 32; ++r) {
                float4 f = *(const float4*)&ftile[r * IND + k];
                acc[r] += f.x * w0 + f.y * w1 + f.z * w2 + f.w * w3;
            }
        }
    }
    for (int r = 0; r < 32; ++r) pre_d[(size_t)(r0 + r) * FOURH + col] = f2bf(acc[r]);
}

// ---------------------------------------------------------------- persistent bidirectional LSTM
// WAVE-AUTONOMOUS: 512 blocks x 64 threads (1 wave each); 256 waves/dir; each
// wave owns 2 hidden units. Per step, lane l polls 8 tagged words k=l+64i
// (independent addresses -> pipelined), computes 8x8 partial MACs from 16
// NAMED float4 weight registers, then a 6-step x 8-value shfl_xor butterfly
// replaces the old LDS-red + __syncthreads. Lanes 0-1 add pre, compute gates,
// and publish their 2 units immediately. NO barrier, NO LDS, no inter-wave
// coupling: publish happens as soon as this wave's chain is done (the old
// 8-wave barrier made every WG wait on the global slowest producer each step).
// Exchange protocol (tagged {f32|step} words, relaxed agent atomics,
// single-writer per address, parity-2 double buffer, lead<=1 liveness) is
// byte-identical to the verified baseline. A consumer matching tag t for word
// u proves the owner published t, which proves its init long preceded -> no
// stale-tag false match (prior-run tags never equal the expected tag at the
// same parity before the owner's ordered overwrite).
__global__ __launch_bounds__(64) void lstm_kernel(
        const void* __restrict__ Wh_f, const void* __restrict__ Wh_b,
        const void* __restrict__ h0, const void* __restrict__ c0,
        const unsigned short* __restrict__ pre, float* __restrict__ hsout,
        unsigned long long* hbuf, const int* __restrict__ dflag) {
    const int isf32 = *dflag;
    const int lane = threadIdx.x;
    const int b = blockIdx.x;
    const int dir = b & 1;
    const int wid = b >> 1;          // 0..255
    const int u0 = wid * 2;          // this wave's 2 hidden units

    const void* Wh = dir ? Wh_b : Wh_f;
    const unsigned short* pre_d = pre + (size_t)dir * SEQ * FOURH;
    float* hso = hsout + (size_t)dir * SEQ * HID;
    unsigned long long* hb_d = hbuf + dir * 2 * HID;   // [parity][512] tagged words

    // ---- stage Wh fragment: k = lane + 64*i, cols (gate,unit) packed as
    // A = (g0u0, g0u1, g1u0, g1u1), B = (g2u0, g2u1, g3u0, g3u1) ----
    float4 w0a, w1a, w2a, w3a, w4a, w5a, w6a, w7a;
    float4 w0b, w1b, w2b, w3b, w4b, w5b, w6b, w7b;
    if (isf32) {
        const float* W = (const float*)Wh;
#define LDWI(i) { const float* p = W + (size_t)(lane + 64 * i) * FOURH; \
        w##i##a = make_float4(p[0 * HID + u0], p[0 * HID + u0 + 1], p[1 * HID + u0], p[1 * HID + u0 + 1]); \
        w##i##b = make_float4(p[2 * HID + u0], p[2 * HID + u0 + 1], p[3 * HID + u0], p[3 * HID + u0 + 1]); }
        LDWI(0) LDWI(1) LDWI(2) LDWI(3) LDWI(4) LDWI(5) LDWI(6) LDWI(7)
#undef LDWI
    } else {
        const unsigned short* W = (const unsigned short*)Wh;
#define LDWI(i) { const unsigned short* p = W + (size_t)(lane + 64 * i) * FOURH; \
        w##i##a = make_float4(bf2f(p[0 * HID + u0]), bf2f(p[0 * HID + u0 + 1]), bf2f(p[1 * HID + u0]), bf2f(p[1 * HID + u0 + 1])); \
        w##i##b = make_float4(bf2f(p[2 * HID + u0]), bf2f(p[2 * HID + u0 + 1]), bf2f(p[3 * HID + u0]), bf2f(p[3 * HID + u0 + 1])); }
        LDWI(0) LDWI(1) LDWI(2) LDWI(3) LDWI(4) LDWI(5) LDWI(6) LDWI(7)
#undef LDWI
    }

    float creg = 0.f;
    unsigned short zn0 = 0, zn1 = 0, zn2 = 0, zn3 = 0;   // prefetched pre (bf16)
    if (lane < 2) {
        creg = ldf(c0, dir * HID + u0 + lane, isf32);
        // single-writer init (this lane is also the sole publisher of these
        // addresses): parity0 = h0 tagged 0; parity1 = INVALID.
        float h0v = ldf(h0, dir * HID + u0 + lane, isf32);
        __hip_atomic_store(&hb_d[u0 + lane],
                           (unsigned long long)__float_as_uint(h0v),
                           __ATOMIC_RELAXED, __HIP_MEMORY_SCOPE_AGENT);
        __hip_atomic_store(&hb_d[HID + u0 + lane],
                           ((unsigned long long)TAG_INVALID << 32),
                           __ATOMIC_RELAXED, __HIP_MEMORY_SCOPE_AGENT);
        int t0 = dir ? (SEQ - 1) : 0;
        zn0 = pre_d[(size_t)t0 * FOURH + 0 * HID + u0 + lane];
        zn1 = pre_d[(size_t)t0 * FOURH + 1 * HID + u0 + lane];
        zn2 = pre_d[(size_t)t0 * FOURH + 2 * HID + u0 + lane];
        zn3 = pre_d[(size_t)t0 * FOURH + 3 * HID + u0 + lane];
    }
    asm volatile("s_waitcnt vmcnt(0)" ::: "memory");   // inits on their way out

    for (int s = 0; s < SEQ; ++s) {
        const int t = dir ? (SEQ - 1 - s) : s;

        // ---- poll 8 tagged words: k = lane + 64*i (pipelined, distinct lines) ----
        const unsigned long long* base = &hb_d[(s & 1) * HID + lane];
        const unsigned e = (unsigned)s;
#define LDP(off) __hip_atomic_load(base + (off), __ATOMIC_RELAXED, __HIP_MEMORY_SCOPE_AGENT)
        unsigned long long v0 = LDP(0),   v1 = LDP(64),  v2 = LDP(128), v3 = LDP(192),
                           v4 = LDP(256), v5 = LDP(320), v6 = LDP(384), v7 = LDP(448);
        while (!((unsigned)(v0 >> 32) == e && (unsigned)(v1 >> 32) == e &&
                 (unsigned)(v2 >> 32) == e && (unsigned)(v3 >> 32) == e &&
                 (unsigned)(v4 >> 32) == e && (unsigned)(v5 >> 32) == e &&
                 (unsigned)(v6 >> 32) == e && (unsigned)(v7 >> 32) == e)) {
            if ((unsigned)(v0 >> 32) != e) v0 = LDP(0);
            if ((unsigned)(v1 >> 32) != e) v1 = LDP(64);
            if ((unsigned)(v2 >> 32) != e) v2 = LDP(128);
            if ((unsigned)(v3 >> 32) != e) v3 = LDP(192);
            if ((unsigned)(v4 >> 32) != e) v4 = LDP(256);
            if ((unsigned)(v5 >> 32) != e) v5 = LDP(320);
            if ((unsigned)(v6 >> 32) != e) v6 = LDP(384);
            if ((unsigned)(v7 >> 32) != e) v7 = LDP(448);
        }
#undef LDP

        // lanes 0-1: consume prefetched pre, issue next prefetch
        float zc0 = 0.f, zc1 = 0.f, zc2 = 0.f, zc3 = 0.f;
        if (lane < 2) {
            zc0 = bf2f(zn0); zc1 = bf2f(zn1); zc2 = bf2f(zn2); zc3 = bf2f(zn3);
            if (s + 1 < SEQ) {
                int tn = dir ? (SEQ - 2 - s) : (s + 1);
                zn0 = pre_d[(size_t)tn * FOURH + 0 * HID + u0 + lane];
                zn1 = pre_d[(size_t)tn * FOURH + 1 * HID + u0 + lane];
                zn2 = pre_d[(size_t)tn * FOURH + 2 * HID + u0 + lane];
                zn3 = pre_d[(size_t)tn * FOURH + 3 * HID + u0 + lane];
            }
        }

        // ---- partial MACs: 8 k-values x 8 gate-cols ----
        float aAx = 0.f, aAy = 0.f, aAz = 0.f, aAw = 0.f;
        float aBx = 0.f, aBy = 0.f, aBz = 0.f, aBw = 0.f;
#define MACI(i) { float hf = __uint_as_float((unsigned)v##i); \
        aAx += hf * w##i##a.x; aAy += hf * w##i##a.y; aAz += hf * w##i##a.z; aAw += hf * w##i##a.w; \
        aBx += hf * w##i##b.x; aBy += hf * w##i##b.y; aBz += hf * w##i##b.z; aBw += hf * w##i##b.w; }
        MACI(0) MACI(1) MACI(2) MACI(3) MACI(4) MACI(5) MACI(6) MACI(7)
#undef MACI

        // ---- 6-step butterfly: sum each of the 8 cols over all 64 lanes ----
#define RED(off) { \
        aAx += __shfl_xor(aAx, off, 64); aAy += __shfl_xor(aAy, off, 64); \
        aAz += __shfl_xor(aAz, off, 64); aAw += __shfl_xor(aAw, off, 64); \
        aBx += __shfl_xor(aBx, off, 64); aBy += __shfl_xor(aBy, off, 64); \
        aBz += __shfl_xor(aBz, off, 64); aBw += __shfl_xor(aBw, off, 64); }
        RED(1) RED(2) RED(4) RED(8) RED(16) RED(32)
#undef RED

        // ---- gates + state update + publish (lanes 0-1, fully independent) ----
        if (lane < 2) {
            float z0 = (lane ? aAy : aAx) + zc0;   // gate i
            float z1 = (lane ? aAw : aAz) + zc1;   // gate f
            float z2 = (lane ? aBy : aBx) + zc2;   // gate g
            float z3 = (lane ? aBw : aBz) + zc3;   // gate o
            z0 = satz(z0); z1 = satz(z1); z2 = satz(z2); z3 = satz(z3);
            float ig = fsigm(z0);
            float fg = fsigm(z1);
            float gg = ftanhf(z2);
            float og = fsigm(z3);
            float cnew = fg * creg + ig * gg;
            creg = cnew;
            float hnew = og * ftanhf(satz(cnew));
            unsigned long long w = ((unsigned long long)(unsigned)(s + 1) << 32)
                                 | (unsigned long long)__float_as_uint(hnew);
            __hip_atomic_store(&hb_d[((s + 1) & 1) * HID + u0 + lane], w,
                               __ATOMIC_RELAXED, __HIP_MEMORY_SCOPE_AGENT);
            hso[(size_t)t * HID + u0 + lane] = hnew;
        }
    }
}

// ---------------------------------------------------------------- outproj + log_softmax + (last block) viterbi
__global__ __launch_bounds__(64) void outproj_kernel(const float* __restrict__ hsout,
        const void* __restrict__ W_out, const void* __restrict__ b_out,
        float* __restrict__ out_scores,
        const void* __restrict__ trans, const void* __restrict__ strans,
        const void* __restrict__ etrans, float* __restrict__ out_path,
        unsigned* __restrict__ vcnt, const int* __restrict__ dflag) {
    __shared__ unsigned char hist[SEQ][NT];
    const int isf32 = *dflag;
    int t = blockIdx.x;
    int lane = threadIdx.x;
    const float* hf = hsout + (size_t)t * HID;
    const float* hb = hsout + (size_t)SEQ * HID + (size_t)t * HID;
    float acc[NT];
#pragma unroll
    for (int j = 0; j < NT; ++j) acc[j] = 0.f;
    for (int k = lane; k < HID; k += 64) {
        float a = hf[k], b2 = hb[k];
#pragma unroll
        for (int j = 0; j < NT; ++j)
            acc[j] += a * ldf(W_out, (size_t)k * NT + j, isf32)
                    + b2 * ldf(W_out, (size_t)(HID + k) * NT + j, isf32);
    }
#pragma unroll
    for (int off = 32; off >= 1; off >>= 1) {
#pragma unroll
        for (int j = 0; j < NT; ++j) acc[j] += __shfl_xor(acc[j], off, 64);
    }
    float o[NT];
    float m = -1e30f;
#pragma unroll
    for (int j = 0; j < NT; ++j) { o[j] = acc[j] + ldf(b_out, j, isf32); m = fmaxf(m, o[j]); }
    float lse = 0.f;
#pragma unroll
    for (int j = 0; j < NT; ++j) lse += expf(o[j] - m);
    lse = m + logf(lse);
    // agent-scope atomic stores -> LLC (visible to the viterbi block without fences)
    if (lane < NT)
        __hip_atomic_store(&out_scores[t * NT + lane], o[lane] - lse,
                           __ATOMIC_RELAXED, __HIP_MEMORY_SCOPE_AGENT);
    __builtin_amdgcn_s_waitcnt(0);   // stores ack'd at LLC before the arrival add

    unsigned old = 0;
    if (lane == 0) old = atomicAdd(vcnt, 1u);
    old = __shfl(old, 0, 64);
    if (old != SEQ - 1) return;

    // ---- last block: all emissions at LLC; run viterbi inline (8-deep prefetch) ----
    const float* em = out_scores;
    int j = lane < NT ? lane : 0;
    float tr[NT];
#pragma unroll
    for (int i = 0; i < NT; ++i) tr[i] = ldf(trans, i * NT + j, isf32);
#define EML(tt) __hip_atomic_load(&em[(size_t)(tt) * NT + j], __ATOMIC_RELAXED, __HIP_MEMORY_SCOPE_AGENT)
    float score = ldf(strans, j, isf32) + EML(0);
    float c0 = EML(1), c1 = EML(2), c2 = EML(3), c3 = EML(4),
          c4 = EML(5), c5 = EML(6), c6 = EML(7), c7 = EML(8);
#define VSTEP(PE, TT) { \
    float best = -1e30f; int arg = 0; \
    _Pragma("unroll") \
    for (int i = 0; i < NT; ++i) { \
        float si = __shfl(score, i, 64); \
        float cand = si + tr[i]; \
        if (cand > best) { best = cand; arg = i; } \
    } \
    if (lane < NT) hist[TT][lane] = (unsigned char)arg; \
    score = best + PE; }
    for (int tb = 1; tb < SEQ; tb += 8) {
        int nb = tb + 8;
        float n0 = 0.f, n1 = 0.f, n2 = 0.f, n3 = 0.f, n4 = 0.f, n5 = 0.f, n6 = 0.f, n7 = 0.f;
        if (nb + 0 < SEQ) n0 = EML(nb + 0);
        if (nb + 1 < SEQ) n1 = EML(nb + 1);
        if (nb + 2 < SEQ) n2 = EML(nb + 2);
        if (nb + 3 < SEQ) n3 = EML(nb + 3);
        if (nb + 4 < SEQ) n4 = EML(nb + 4);
        if (nb + 5 < SEQ) n5 = EML(nb + 5);
        if (nb + 6 < SEQ) n6 = EML(nb + 6);
        if (nb + 7 < SEQ) n7 = EML(nb + 7);
        VSTEP(c0, tb + 0)
        if (tb + 1 < SEQ) VSTEP(c1, tb + 1)
        if (tb + 2 < SEQ) VSTEP(c2, tb + 2)
        if (tb + 3 < SEQ) VSTEP(c3, tb + 3)
        if (tb + 4 < SEQ) VSTEP(c4, tb + 4)
        if (tb + 5 < SEQ) VSTEP(c5, tb + 5)
        if (tb + 6 < SEQ) VSTEP(c6, tb + 6)
        if (tb + 7 < SEQ) VSTEP(c7, tb + 7)
        c0 = n0; c1 = n1; c2 = n2; c3 = n3; c4 = n4; c5 = n5; c6 = n6; c7 = n7;
    }
#undef VSTEP
#undef EML
    score += ldf(etrans, j, isf32);
    float bmax = -1e30f;
    int last = 0;
#pragma unroll
    for (int i = 0; i < NT; ++i) {
        float si = __shfl(score, i, 64);
        if (si > bmax) { bmax = si; last = i; }
    }
    if (lane == 0) {
        int cur = last;
        out_path[SEQ - 1] = (float)cur;
        for (int tt = SEQ - 1; tt >= 1; --tt) {
            cur = hist[tt][cur];
            out_path[tt - 1] = (float)cur;
        }
    }
}

// ---------------------------------------------------------------- launch
extern "C" void kernel_launch(void* const* d_in, const int* in_sizes, int n_in,
                              void* d_out, int out_size, void* d_ws, size_t ws_size,
                              hipStream_t stream) {
    const int* x      = (const int*)d_in[0];
    const int* casing = (const int*)d_in[1];
    const int* posi   = (const int*)d_in[2];
    const void* h0    = d_in[3];
    const void* c0    = d_in[4];
    const void* W_emb = d_in[5];
    const void* W_cas = d_in[6];
    const void* W_pos = d_in[7];
    const void* Wx_f  = d_in[8];
    const void* Wh_f  = d_in[9];
    const void* b_f   = d_in[10];
    const void* Wx_b  = d_in[11];
    const void* Wh_b  = d_in[12];
    const void* b_b   = d_in[13];
    const void* W_out = d_in[14];
    const void* b_out = d_in[15];
    const void* trans = d_in[16];
    const void* strans = d_in[17];
    const void* etrans = d_in[18];

    // workspace layout (~12.6 MB)
    char* ws = (char*)d_ws;
    int* dflag          = (int*)(ws + 448);
    unsigned* vcnt      = (unsigned*)(ws + 456);
    unsigned short* pre = (unsigned short*)(ws + 512);            // 2*1024*2048 bf16 = 8,388,608
    float* hsout        = (float*)(ws + 512 + 8388608);           // 2*1024*512 f32 = 4,194,304
    unsigned long long* hbuf = (unsigned long long*)(ws + 512 + 8388608 + 4194304); // 2*2*512 u64

    // d_out is FLOAT32: 13312 tag_scores then 1024 path values
    float* out_scores = (float*)d_out;
    float* out_path   = out_scores + SEQ * NT;

    detect_kernel<<<1, 64, 0, stream>>>((const unsigned short*)W_emb, dflag, vcnt);

    dim3 g2(8, 32, 2);
    pre_gemm_kernel<<<g2, 256, 0, stream>>>(x, casing, posi, W_emb, W_cas, W_pos,
                                            Wx_f, b_f, Wx_b, b_b, pre, dflag);

    lstm_kernel<<<512, 64, 0, stream>>>(
        Wh_f, Wh_b, h0, c0, pre, hsout, hbuf, dflag);

    outproj_kernel<<<SEQ, 64, 0, stream>>>(hsout, W_out, b_out, out_scores,
                                           trans, strans, etrans, out_path, vcnt, dflag);
}

// Round 9
// 2281.155 us; speedup vs baseline: 2.0118x; 2.0118x over previous
//
#include <hip/hip_runtime.h>
#include <hip/hip_bf16.h>
#include <math.h>

#define SEQ 1024
#define HID 512
#define FOURH 2048
#define IND 400
#define NT 13

#define NWG_DIR 32
#define LSTM_THREADS 512
#define JPW 16      // hidden units per WG
#define WCOLS 64    // gate columns per WG (4 gates * 16 units)
#define TAG_INVALID 0xFFFFFFFFu

__device__ __forceinline__ float bf2f(unsigned short u) {
    union { unsigned u32; float f; } v;
    v.u32 = ((unsigned)u) << 16;
    return v.f;
}

__device__ __forceinline__ unsigned short f2bf(float f) {
    union { float f; unsigned u; } v;
    v.f = f;
    unsigned u = v.u;
    unsigned rounding = 0x7FFFu + ((u >> 16) & 1u);
    u += rounding;
    return (unsigned short)(u >> 16);
}

// dtype-agnostic float load: isf32 selects f32 vs bf16 interpretation
__device__ __forceinline__ float ldf(const void* p, size_t i, int isf32) {
    return isf32 ? ((const float*)p)[i] : bf2f(((const unsigned short*)p)[i]);
}

// fast transcendentals: v_exp_f32 / v_rcp_f32 based; abs err ~1e-7
__device__ __forceinline__ float fsigm(float x) {
    return __builtin_amdgcn_rcpf(1.f + __builtin_amdgcn_exp2f(-1.44269504f * x));
}
__device__ __forceinline__ float ftanhf(float x) {
    return 1.f - 2.f * __builtin_amdgcn_rcpf(__builtin_amdgcn_exp2f(2.88539008f * x) + 1.f);
}
// saturating clamp (also squashes NaN from any garbage input)
__device__ __forceinline__ float satz(float z) { return fminf(fmaxf(z, -60.f), 60.f); }

// ---------------------------------------------------------------- input dtype detection + counter zero
__global__ __launch_bounds__(64) void detect_kernel(const unsigned short* __restrict__ w,
                                                    int* __restrict__ flag,
                                                    unsigned* __restrict__ vcnt) {
    int lane = threadIdx.x;
    int cnt = 0;
    for (int i = 0; i < 4; ++i) {
        unsigned short u = w[2 * (lane * 4 + i)];   // low half if buffer is f32
        int e = (u >> 7) & 0xFF;
        if (e >= 90 && e < 127) cnt++;
    }
#pragma unroll
    for (int off = 32; off >= 1; off >>= 1) cnt += __shfl_xor(cnt, off, 64);
    if (lane == 0) *flag = (cnt < 128) ? 1 : 0;    // 1 => inputs are float32
    if (lane == 1) *vcnt = 0;                      // outproj->viterbi completion counter
}

// ---------------------------------------------------------------- pre = feat @ Wx + b (embed fused, both dirs), bf16 out
__global__ __launch_bounds__(256) void pre_gemm_kernel(
        const int* __restrict__ x, const int* __restrict__ cas, const int* __restrict__ pos,
        const void* __restrict__ W_emb, const void* __restrict__ W_cas, const void* __restrict__ W_pos,
        const void* __restrict__ Wx_f, const void* __restrict__ b_f,
        const void* __restrict__ Wx_b, const void* __restrict__ b_b,
        unsigned short* __restrict__ pre, const int* __restrict__ dflag) {
    __shared__ float ftile[32 * IND];    // 51.2 KB
    __shared__ int idxs[96];
    const int isf32 = *dflag;
    int dir = blockIdx.z;
    const void* Wx = dir ? Wx_b : Wx_f;
    const void* bb = dir ? b_b : b_f;
    unsigned short* pre_d = pre + (size_t)dir * SEQ * FOURH;
    int r0 = blockIdx.y * 32;
    int col = blockIdx.x * 256 + threadIdx.x;
    int tid = threadIdx.x;

    if (tid < 32)       idxs[tid] = x[r0 + tid];
    else if (tid < 64)  idxs[tid] = cas[r0 + tid - 32];
    else if (tid < 96)  idxs[tid] = pos[r0 + tid - 64];
    __syncthreads();

    for (int idx = tid; idx < 32 * IND; idx += 256) {
        int r = idx / IND;
        int e = idx - r * IND;
        float v;
        if (e < 300)      v = ldf(W_emb, (size_t)idxs[r] * 300 + e, isf32);
        else if (e < 350) v = ldf(W_cas, (size_t)idxs[32 + r] * 50 + (e - 300), isf32);
        else              v = ldf(W_pos, (size_t)idxs[64 + r] * 50 + (e - 350), isf32);
        ftile[idx] = v;
    }
    __syncthreads();

    float acc[32];
    float bias = ldf(bb, col, isf32);
#pragma unroll
    for (int r = 0; r < 32; ++r) acc[r] = bias;

    if (isf32) {
        const float* W = (const float*)Wx;
        for (int kk = 0; kk < 100; ++kk) {
            int k = kk * 4;
            float w0 = W[(size_t)(k + 0) * FOURH + col];
            float w1 = W[(size_t)(k + 1) * FOURH + col];
            float w2 = W[(size_t)(k + 2) * FOURH + col];
            float w3 = W[(size_t)(k + 3) * FOURH + col];
#pragma unroll
            for (int r = 0; r < 32; ++r) {
                float4 f = *(const float4*)&ftile[r * IND + k];
                acc[r] += f.x * w0 + f.y * w1 + f.z * w2 + f.w * w3;
            }
        }
    } else {
        const unsigned short* W = (const unsigned short*)Wx;
        for (int kk = 0; kk < 100; ++kk) {
            int k = kk * 4;
            float w0 = bf2f(W[(size_t)(k + 0) * FOURH + col]);
            float w1 = bf2f(W[(size_t)(k + 1) * FOURH + col]);
            float w2 = bf2f(W[(size_t)(k + 2) * FOURH + col]);
            float w3 = bf2f(W[(size_t)(k + 3) * FOURH + col]);
#pragma unroll
            for (int r = 0; r < 32; ++r) {
                float4 f = *(const float4*)&ftile[r * IND + k];
                acc[r] += f.x * w0 + f.y * w1 + f.z * w2 + f.w * w3;
            }
        }
    }
    for (int r = 0; r < 32; ++r) pre_d[(size_t)(r0 + r) * FOURH + col] = f2bf(acc[r]);
}

// ---------------------------------------------------------------- persistent bidirectional LSTM
// Verified R0/R4 structure (64 WGs x 512 thr, Wh in 16 NAMED float4 regs,
// readlane matvec, ONE barrier/step) with two in-structure changes:
// (1) 64-LANE EPILOGUE: post-barrier tail spread over wave 0's 64 lanes
//     (lane = unit*4+gate: 8 scalar LDS reads + 1 activation), gates gathered
//     into publisher lanes via 3 shfl_xor -> shorter serial tail than the old
//     16-lane x (8 float4 + 4 serial transcendentals) version.
// (2) DUAL-ADDRESS PUBLISH: producer writes each tagged word {f32|step} to two
//     distinct lines (2 stores, ~30cy); consumer alternates polls A/B so the
//     sampling period is ~RT/2 (R7 showed same-address reissues get merged ->
//     period == full RT). Same single-writer discipline (one thread writes
//     both copies + their init), same tag protocol, same lead<=1 liveness.
__global__ __launch_bounds__(LSTM_THREADS, 2) void lstm_kernel(
        const void* __restrict__ Wh_f, const void* __restrict__ Wh_b,
        const void* __restrict__ h0, const void* __restrict__ c0,
        const unsigned short* __restrict__ pre, float* __restrict__ hsout,
        unsigned long long* hbuf, const int* __restrict__ dflag) {
    __shared__ float red[2][8 * WCOLS];  // [parity][seg][unit][gate] partial dots (4 KB)

    const int isf32 = *dflag;
    const int tid = threadIdx.x;
    const int b = blockIdx.x;
    const int dir = b & 1;
    const int g = b >> 1;            // 0..31
    const int j0 = g * JPW;          // 16-unit slice

    const void* Wh = dir ? Wh_b : Wh_f;
    const unsigned short* pre_d = pre + (size_t)dir * SEQ * FOURH;
    float* hso = hsout + (size_t)dir * SEQ * HID;
    unsigned long long* hb_d  = hbuf + dir * 2 * HID;          // copy A: [parity][512]
    unsigned long long* hb2_d = hbuf + 4096 + dir * 2 * HID;   // copy B (+32 KB)

    const int seg  = tid >> 6;          // 0..7 == wave id; k-range seg*64..+63
    const int col  = tid & 63;          // 0..63
    const int unit = col & 15;
    const int gate = col >> 4;
    const int gcol = gate * HID + j0 + unit;
    const int redoff = seg * WCOLS + unit * 4 + gate;

    // epilogue roles (wave 0 only; tid<64 is wave-uniform -> no divergence)
    const int isep  = (tid < 64);
    const int eunit = tid >> 2;         // 0..15
    const int egate = tid & 3;          // 0..3
    const int ispub = isep && (egate == 0);

    // ---- stage Wh into 16 NAMED float4 registers ----
    float4 w0, w1, w2, w3, w4, w5, w6, w7, w8, w9, w10, w11, w12, w13, w14, w15;
    if (isf32) {
        const float* wp = (const float*)Wh + (size_t)(seg * 64) * FOURH + gcol;
#define LDW(i) w##i = make_float4(wp[(size_t)(4*i+0)*FOURH], wp[(size_t)(4*i+1)*FOURH], \
                                  wp[(size_t)(4*i+2)*FOURH], wp[(size_t)(4*i+3)*FOURH])
        LDW(0); LDW(1); LDW(2); LDW(3); LDW(4); LDW(5); LDW(6); LDW(7);
        LDW(8); LDW(9); LDW(10); LDW(11); LDW(12); LDW(13); LDW(14); LDW(15);
#undef LDW
    } else {
        const unsigned short* wp = (const unsigned short*)Wh + (size_t)(seg * 64) * FOURH + gcol;
#define LDW(i) w##i = make_float4(bf2f(wp[(size_t)(4*i+0)*FOURH]), bf2f(wp[(size_t)(4*i+1)*FOURH]), \
                                  bf2f(wp[(size_t)(4*i+2)*FOURH]), bf2f(wp[(size_t)(4*i+3)*FOURH]))
        LDW(0); LDW(1); LDW(2); LDW(3); LDW(4); LDW(5); LDW(6); LDW(7);
        LDW(8); LDW(9); LDW(10); LDW(11); LDW(12); LDW(13); LDW(14); LDW(15);
#undef LDW
    }

    float creg = 0.f;
    unsigned short zn = 0;   // prefetched pre (bf16), one (gate,unit) scalar per lane
    if (isep) {
        if (ispub) {
            creg = ldf(c0, dir * HID + j0 + eunit, isf32);
            // single-writer init of BOTH copies, both parities (this lane is
            // also the sole publisher of these 4 addresses; program order
            // protects init vs later publish).
            float h0v = ldf(h0, dir * HID + j0 + eunit, isf32);
            unsigned long long wv = (unsigned long long)__float_as_uint(h0v);
            unsigned long long iv = ((unsigned long long)TAG_INVALID << 32);
            __hip_atomic_store(&hb_d[j0 + eunit],        wv, __ATOMIC_RELAXED, __HIP_MEMORY_SCOPE_AGENT);
            __hip_atomic_store(&hb2_d[j0 + eunit],       wv, __ATOMIC_RELAXED, __HIP_MEMORY_SCOPE_AGENT);
            __hip_atomic_store(&hb_d[HID + j0 + eunit],  iv, __ATOMIC_RELAXED, __HIP_MEMORY_SCOPE_AGENT);
            __hip_atomic_store(&hb2_d[HID + j0 + eunit], iv, __ATOMIC_RELAXED, __HIP_MEMORY_SCOPE_AGENT);
        }
        int t0 = dir ? (SEQ - 1) : 0;
        zn = pre_d[(size_t)t0 * FOURH + egate * HID + j0 + eunit];
    }
    __syncthreads();   // drains vmcnt: own tagged words on their way before anyone spins

    for (int s = 0; s < SEQ; ++s) {
        const int t = dir ? (SEQ - 1 - s) : s;

        // ---- alternating dual-address poll on own tagged word (lane owns k=tid) ----
        unsigned hu;
        {
            const unsigned long long* A = &hb_d[(s & 1) * HID + tid];
            const unsigned long long* B = &hb2_d[(s & 1) * HID + tid];
            const unsigned expect = (unsigned)s;
            unsigned long long va = __hip_atomic_load(A, __ATOMIC_RELAXED, __HIP_MEMORY_SCOPE_AGENT);
            unsigned long long vb = __hip_atomic_load(B, __ATOMIC_RELAXED, __HIP_MEMORY_SCOPE_AGENT);
            for (;;) {
                if ((unsigned)(va >> 32) == expect) { hu = (unsigned)va; break; }
                va = __hip_atomic_load(A, __ATOMIC_RELAXED, __HIP_MEMORY_SCOPE_AGENT);
                if ((unsigned)(vb >> 32) == expect) { hu = (unsigned)vb; break; }
                vb = __hip_atomic_load(B, __ATOMIC_RELAXED, __HIP_MEMORY_SCOPE_AGENT);
            }
        }

        // epilogue lanes: consume prefetched pre, issue next prefetch
        float zc = 0.f;
        if (isep) {
            zc = bf2f(zn);
            if (s + 1 < SEQ) {
                int tn = dir ? (SEQ - 2 - s) : (s + 1);
                zn = pre_d[(size_t)tn * FOURH + egate * HID + j0 + eunit];
            }
        }

        // ---- matvec: h broadcast via readlane (no LDS, no barrier) ----
        float a0 = 0.f, a1 = 0.f, a2 = 0.f, a3 = 0.f;
#define MACQ(i, A) { \
        float hx = __uint_as_float((unsigned)__builtin_amdgcn_readlane((int)hu, 4*i+0)); \
        float hy = __uint_as_float((unsigned)__builtin_amdgcn_readlane((int)hu, 4*i+1)); \
        float hz = __uint_as_float((unsigned)__builtin_amdgcn_readlane((int)hu, 4*i+2)); \
        float hw = __uint_as_float((unsigned)__builtin_amdgcn_readlane((int)hu, 4*i+3)); \
        A += hx * w##i.x + hy * w##i.y + hz * w##i.z + hw * w##i.w; }
        MACQ(0, a0)  MACQ(1, a1)  MACQ(2, a2)  MACQ(3, a3)
        MACQ(4, a0)  MACQ(5, a1)  MACQ(6, a2)  MACQ(7, a3)
        MACQ(8, a0)  MACQ(9, a1)  MACQ(10, a2) MACQ(11, a3)
        MACQ(12, a0) MACQ(13, a1) MACQ(14, a2) MACQ(15, a3)
#undef MACQ
        red[s & 1][redoff] = (a0 + a1) + (a2 + a3);
        __syncthreads();   // the ONE barrier: all 8 waves' red(s) complete

        // ---- 64-lane epilogue: lane = unit*4+gate sums its column, activates;
        //      3 shfl_xor gather the 4 gate values into the publisher lane ----
        if (isep) {
            const float* rp = &red[s & 1][0];
            float z = rp[0 * WCOLS + tid] + rp[1 * WCOLS + tid]
                    + rp[2 * WCOLS + tid] + rp[3 * WCOLS + tid]
                    + rp[4 * WCOLS + tid] + rp[5 * WCOLS + tid]
                    + rp[6 * WCOLS + tid] + rp[7 * WCOLS + tid];
            z = satz(z + zc);
            float vs = fsigm(z);
            float vt = ftanhf(z);
            float v = (egate == 2) ? vt : vs;     // i,f,o: sigmoid; g: tanh
            float x1 = __shfl_xor(v, 1, 64);
            float x2 = __shfl_xor(v, 2, 64);
            float x3 = __shfl_xor(x1, 2, 64);
            if (ispub) {
                float ig = v, fg = x1, gg = x2, og = x3;
                float cnew = fg * creg + ig * gg;
                creg = cnew;
                float hnew = og * ftanhf(satz(cnew));
                unsigned long long w = ((unsigned long long)(unsigned)(s + 1) << 32)
                                     | (unsigned long long)__float_as_uint(hnew);
                const int par = (s + 1) & 1;
                __hip_atomic_store(&hb_d[par * HID + j0 + eunit], w,
                                   __ATOMIC_RELAXED, __HIP_MEMORY_SCOPE_AGENT);
                __hip_atomic_store(&hb2_d[par * HID + j0 + eunit], w,
                                   __ATOMIC_RELAXED, __HIP_MEMORY_SCOPE_AGENT);
                hso[(size_t)t * HID + j0 + eunit] = hnew;
            }
        }
        // no trailing barrier: next iteration's tag-spin + red parity is the sync
    }
}

// ---------------------------------------------------------------- outproj + log_softmax + (last block) viterbi
__global__ __launch_bounds__(64) void outproj_kernel(const float* __restrict__ hsout,
        const void* __restrict__ W_out, const void* __restrict__ b_out,
        float* __restrict__ out_scores,
        const void* __restrict__ trans, const void* __restrict__ strans,
        const void* __restrict__ etrans, float* __restrict__ out_path,
        unsigned* __restrict__ vcnt, const int* __restrict__ dflag) {
    __shared__ unsigned char hist[SEQ][NT];
    const int isf32 = *dflag;
    int t = blockIdx.x;
    int lane = threadIdx.x;
    const float* hf = hsout + (size_t)t * HID;
    const float* hb = hsout + (size_t)SEQ * HID + (size_t)t * HID;
    float acc[NT];
#pragma unroll
    for (int j = 0; j < NT; ++j) acc[j] = 0.f;
    for (int k = lane; k < HID; k += 64) {
        float a = hf[k], b2 = hb[k];
#pragma unroll
        for (int j = 0; j < NT; ++j)
            acc[j] += a * ldf(W_out, (size_t)k * NT + j, isf32)
                    + b2 * ldf(W_out, (size_t)(HID + k) * NT + j, isf32);
    }
#pragma unroll
    for (int off = 32; off >= 1; off >>= 1) {
#pragma unroll
        for (int j = 0; j < NT; ++j) acc[j] += __shfl_xor(acc[j], off, 64);
    }
    float o[NT];
    float m = -1e30f;
#pragma unroll
    for (int j = 0; j < NT; ++j) { o[j] = acc[j] + ldf(b_out, j, isf32); m = fmaxf(m, o[j]); }
    float lse = 0.f;
#pragma unroll
    for (int j = 0; j < NT; ++j) lse += expf(o[j] - m);
    lse = m + logf(lse);
    // agent-scope atomic stores -> LLC (visible to the viterbi block without fences)
    if (lane < NT)
        __hip_atomic_store(&out_scores[t * NT + lane], o[lane] - lse,
                           __ATOMIC_RELAXED, __HIP_MEMORY_SCOPE_AGENT);
    __builtin_amdgcn_s_waitcnt(0);   // stores ack'd at LLC before the arrival add

    unsigned old = 0;
    if (lane == 0) old = atomicAdd(vcnt, 1u);
    old = __shfl(old, 0, 64);
    if (old != SEQ - 1) return;

    // ---- last block: all emissions at LLC; run viterbi inline (8-deep prefetch) ----
    const float* em = out_scores;
    int j = lane < NT ? lane : 0;
    float tr[NT];
#pragma unroll
    for (int i = 0; i < NT; ++i) tr[i] = ldf(trans, i * NT + j, isf32);
#define EML(tt) __hip_atomic_load(&em[(size_t)(tt) * NT + j], __ATOMIC_RELAXED, __HIP_MEMORY_SCOPE_AGENT)
    float score = ldf(strans, j, isf32) + EML(0);
    float c0 = EML(1), c1 = EML(2), c2 = EML(3), c3 = EML(4),
          c4 = EML(5), c5 = EML(6), c6 = EML(7), c7 = EML(8);
#define VSTEP(PE, TT) { \
    float best = -1e30f; int arg = 0; \
    _Pragma("unroll") \
    for (int i = 0; i < NT; ++i) { \
        float si = __shfl(score, i, 64); \
        float cand = si + tr[i]; \
        if (cand > best) { best = cand; arg = i; } \
    } \
    if (lane < NT) hist[TT][lane] = (unsigned char)arg; \
    score = best + PE; }
    for (int tb = 1; tb < SEQ; tb += 8) {
        int nb = tb + 8;
        float n0 = 0.f, n1 = 0.f, n2 = 0.f, n3 = 0.f, n4 = 0.f, n5 = 0.f, n6 = 0.f, n7 = 0.f;
        if (nb + 0 < SEQ) n0 = EML(nb + 0);
        if (nb + 1 < SEQ) n1 = EML(nb + 1);
        if (nb + 2 < SEQ) n2 = EML(nb + 2);
        if (nb + 3 < SEQ) n3 = EML(nb + 3);
        if (nb + 4 < SEQ) n4 = EML(nb + 4);
        if (nb + 5 < SEQ) n5 = EML(nb + 5);
        if (nb + 6 < SEQ) n6 = EML(nb + 6);
        if (nb + 7 < SEQ) n7 = EML(nb + 7);
        VSTEP(c0, tb + 0)
        if (tb + 1 < SEQ) VSTEP(c1, tb + 1)
        if (tb + 2 < SEQ) VSTEP(c2, tb + 2)
        if (tb + 3 < SEQ) VSTEP(c3, tb + 3)
        if (tb + 4 < SEQ) VSTEP(c4, tb + 4)
        if (tb + 5 < SEQ) VSTEP(c5, tb + 5)
        if (tb + 6 < SEQ) VSTEP(c6, tb + 6)
        if (tb + 7 < SEQ) VSTEP(c7, tb + 7)
        c0 = n0; c1 = n1; c2 = n2; c3 = n3; c4 = n4; c5 = n5; c6 = n6; c7 = n7;
    }
#undef VSTEP
#undef EML
    score += ldf(etrans, j, isf32);
    float bmax = -1e30f;
    int last = 0;
#pragma unroll
    for (int i = 0; i < NT; ++i) {
        float si = __shfl(score, i, 64);
        if (si > bmax) { bmax = si; last = i; }
    }
    if (lane == 0) {
        int cur = last;
        out_path[SEQ - 1] = (float)cur;
        for (int tt = SEQ - 1; tt >= 1; --tt) {
            cur = hist[tt][cur];
            out_path[tt - 1] = (float)cur;
        }
    }
}

// ---------------------------------------------------------------- launch
extern "C" void kernel_launch(void* const* d_in, const int* in_sizes, int n_in,
                              void* d_out, int out_size, void* d_ws, size_t ws_size,
                              hipStream_t stream) {
    const int* x      = (const int*)d_in[0];
    const int* casing = (const int*)d_in[1];
    const int* posi   = (const int*)d_in[2];
    const void* h0    = d_in[3];
    const void* c0    = d_in[4];
    const void* W_emb = d_in[5];
    const void* W_cas = d_in[6];
    const void* W_pos = d_in[7];
    const void* Wx_f  = d_in[8];
    const void* Wh_f  = d_in[9];
    const void* b_f   = d_in[10];
    const void* Wx_b  = d_in[11];
    const void* Wh_b  = d_in[12];
    const void* b_b   = d_in[13];
    const void* W_out = d_in[14];
    const void* b_out = d_in[15];
    const void* trans = d_in[16];
    const void* strans = d_in[17];
    const void* etrans = d_in[18];

    // workspace layout (~12.7 MB)
    char* ws = (char*)d_ws;
    int* dflag          = (int*)(ws + 448);
    unsigned* vcnt      = (unsigned*)(ws + 456);
    unsigned short* pre = (unsigned short*)(ws + 512);            // 2*1024*2048 bf16 = 8,388,608
    float* hsout        = (float*)(ws + 512 + 8388608);           // 2*1024*512 f32 = 4,194,304
    // h exchange: copy A at [0..2047] ull, copy B at [4096..6143] ull (48 KB)
    unsigned long long* hbuf = (unsigned long long*)(ws + 512 + 8388608 + 4194304);

    // d_out is FLOAT32: 13312 tag_scores then 1024 path values
    float* out_scores = (float*)d_out;
    float* out_path   = out_scores + SEQ * NT;

    detect_kernel<<<1, 64, 0, stream>>>((const unsigned short*)W_emb, dflag, vcnt);

    dim3 g2(8, 32, 2);
    pre_gemm_kernel<<<g2, 256, 0, stream>>>(x, casing, posi, W_emb, W_cas, W_pos,
                                            Wx_f, b_f, Wx_b, b_b, pre, dflag);

    lstm_kernel<<<2 * NWG_DIR, LSTM_THREADS, 0, stream>>>(
        Wh_f, Wh_b, h0, c0, pre, hsout, hbuf, dflag);

    outproj_kernel<<<SEQ, 64, 0, stream>>>(hsout, W_out, b_out, out_scores,
                                           trans, strans, etrans, out_path, vcnt, dflag);
}